// Round 4
// baseline (89.981 us; speedup 1.0000x reference)
//
#include <hip/hip_runtime.h>

// Problem constants (from reference setup_inputs):
//   pred_emb:   (N=2, C=80, H=512, W=512) float32
//   gt_objmask: (N=2, K=32, H=512, W=512) bool (1 byte/elem)
//   gt_classes: (N=2, K=32) int32
#define N_IMG 2
#define K_OBJ 32
#define C_CH  80
#define HW    (512 * 512)
#define NK    (N_IMG * K_OBJ)

#define BPN 32                    // blocks per (n,k)
#define BT  256                   // threads per block
#define GRID (NK * BPN)           // 2048 blocks
#define SPAN (BPN * BT)           // 8192 thread-slots per (n,k)
#define NV16 (HW / 16)            // 16384 16-elem groups per (n,k)
#define ITERS (NV16 / SPAN)       // = 2, compile-time

// ws layout (floats):
//   [blk][comp][nk], comp in {cnt,s,s2}: 32*3*64 = 6144 floats
//   ws[8192] = ticket counter (uint), zeroed by zero_ticket each call
#define TICKET_OFF 8192

__global__ void zero_ticket(unsigned int* ws_u) {
    ws_u[TICKET_OFF] = 0u;
}

__global__ __launch_bounds__(BT) void fused_kernel(
    const float* __restrict__ pred,
    const unsigned char* __restrict__ mask,
    const int* __restrict__ classes,
    float* __restrict__ ws,
    float* __restrict__ out)
{
    const int nk  = blockIdx.x / BPN;
    const int blk = blockIdx.x % BPN;
    const int n   = nk / K_OBJ;
    const int c   = classes[nk];

    const float4* __restrict__ embv =
        (const float4*)(pred + (size_t)(n * C_CH + c) * HW);
    const uint4* __restrict__ mv =
        (const uint4*)(mask + (size_t)nk * HW);

    unsigned int cnt_i = 0;
    float s = 0.0f, s2 = 0.0f;
    const int base = blk * BT + threadIdx.x;

#define ACCB(w, b, e) do {                                   \
        float v_ = (((w) >> (8*(b))) & 1u) ? (e) : 0.0f;     \
        s += v_; s2 = fmaf(v_, (e), s2);                     \
    } while (0)

    #pragma unroll
    for (int it = 0; it < ITERS; ++it) {
        const int i = base + it * SPAN;
        const uint4  m  = mv[i];
        const float4 e0 = embv[4*i + 0];
        const float4 e1 = embv[4*i + 1];
        const float4 e2 = embv[4*i + 2];
        const float4 e3 = embv[4*i + 3];

        unsigned int t = m.x + m.y + m.z + m.w;   // per-byte sums <= 4
        cnt_i += (t * 0x01010101u) >> 24;         // sum of 16 mask bytes

        ACCB(m.x,0,e0.x); ACCB(m.x,1,e0.y); ACCB(m.x,2,e0.z); ACCB(m.x,3,e0.w);
        ACCB(m.y,0,e1.x); ACCB(m.y,1,e1.y); ACCB(m.y,2,e1.z); ACCB(m.y,3,e1.w);
        ACCB(m.z,0,e2.x); ACCB(m.z,1,e2.y); ACCB(m.z,2,e2.z); ACCB(m.z,3,e2.w);
        ACCB(m.w,0,e3.x); ACCB(m.w,1,e3.y); ACCB(m.w,2,e3.z); ACCB(m.w,3,e3.w);
    }
#undef ACCB

    float cnt = (float)cnt_i;
    #pragma unroll
    for (int off = 32; off > 0; off >>= 1) {
        cnt += __shfl_down(cnt, off);
        s   += __shfl_down(s,   off);
        s2  += __shfl_down(s2,  off);
    }

    __shared__ float sm[3][BT / 64];
    __shared__ int is_last;
    const int lane = threadIdx.x & 63;
    const int wv   = threadIdx.x >> 6;
    if (lane == 0) { sm[0][wv] = cnt; sm[1][wv] = s; sm[2][wv] = s2; }
    __syncthreads();

    if (threadIdx.x == 0) {
        float tc = 0.f, ts = 0.f, t2 = 0.f;
        #pragma unroll
        for (int w = 0; w < BT / 64; ++w) {
            tc += sm[0][w]; ts += sm[1][w]; t2 += sm[2][w];
        }
        float* dst = ws + (size_t)blk * 3 * NK;
        dst[0 * NK + nk] = tc;
        dst[1 * NK + nk] = ts;
        dst[2 * NK + nk] = t2;
        // release partials, then take a ticket (device-scope)
        __threadfence();
        unsigned int old = atomicAdd((unsigned int*)ws + TICKET_OFF, 1u);
        is_last = (old == GRID - 1) ? 1 : 0;
    }
    __syncthreads();
    if (!is_last) return;

    // ---- last block: finalize (first wave only) ----
    __threadfence();                     // acquire all partials
    const int t = threadIdx.x;
    if (t >= 64) {
        // reset ticket for the next call while wave 0 finalizes
        if (t == 64) *((unsigned int*)ws + TICKET_OFF) = 0u;
        return;
    }

    float fcnt = 0.f, fs = 0.f, fs2 = 0.f;
    #pragma unroll 4
    for (int b = 0; b < BPN; ++b) {
        const float* src = ws + (size_t)b * 3 * NK;
        fcnt += src[0 * NK + t];
        fs   += src[1 * NK + t];
        fs2  += src[2 * NK + t];
    }
    const bool valid = fcnt > 0.0f;
    const float safe = valid ? fcnt : 1.0f;
    const float mean = valid ? fs / safe : 0.0f;
    const float var  = valid ? fs2 / safe - mean * mean : 0.0f;

    __shared__ float smean[NK];
    __shared__ int   scls[NK];
    smean[t] = mean;
    scls[t]  = classes[t];
    // wave 0 only past this point: lane-sync is implicit within a wave,
    // but LDS writes need a waitcnt barrier -> use __syncthreads-free fence
    __builtin_amdgcn_s_waitcnt(0);       // lgkmcnt(0)/vmcnt(0) drain

    const int j  = t & 31;              // instance within image
    const int nb = t & 32;              // image base (0 or 32)
    float part = (mean * mean + var) * (1.0f / K_OBJ);   // reg + intra share
    const int cj = scls[t];
    for (int k = j + 1; k < K_OBJ; ++k) {
        if (scls[nb + k] == cj) {
            float d = mean - smean[nb + k];
            float val = 1.0f - d * d;
            part += (val > 0.0f) ? val : 0.0f;
        }
    }
    #pragma unroll
    for (int off = 32; off > 0; off >>= 1) part += __shfl_down(part, off);
    if (t == 0) out[0] = part * (0.1f / N_IMG);
}

extern "C" void kernel_launch(void* const* d_in, const int* in_sizes, int n_in,
                              void* d_out, int out_size, void* d_ws, size_t ws_size,
                              hipStream_t stream) {
    const float* pred = (const float*)d_in[0];
    const unsigned char* mask = (const unsigned char*)d_in[1];
    const int* classes = (const int*)d_in[2];
    float* out = (float*)d_out;
    float* ws = (float*)d_ws;

    zero_ticket<<<1, 1, 0, stream>>>((unsigned int*)ws);
    fused_kernel<<<GRID, BT, 0, stream>>>(pred, mask, classes, ws, out);
}

// Round 6
// 28.057 us; speedup vs baseline: 3.2071x; 3.2071x over previous
//
#include <hip/hip_runtime.h>

// Problem constants (from reference setup_inputs):
//   pred_emb:   (N=2, C=80, H=512, W=512) float32
//   gt_objmask: (N=2, K=32, H=512, W=512) bool (1 byte/elem)
//   gt_classes: (N=2, K=32) int32
#define N_IMG 2
#define K_OBJ 32
#define C_CH  80
#define HW    (512 * 512)
#define NK    (N_IMG * K_OBJ)

#define BPN 32                    // blocks per (n,k)
#define BT  256                   // threads per block
#define SPAN (BPN * BT)           // 8192 thread-slots per (n,k)
#define NV16 (HW / 16)            // 16384 16-elem groups per (n,k)

// Native clang vector types (required by __builtin_nontemporal_load).
typedef float        f32x4 __attribute__((ext_vector_type(4)));
typedef unsigned int u32x4 __attribute__((ext_vector_type(4)));

// ws layout: ws[blk][comp][nk], comp in {cnt,s,s2}; 32*3*64 floats = 24 KB.
// Every slot is written every call by partial_kernel, so no zeroing needed.

__global__ __launch_bounds__(BT) void partial_kernel(
    const float* __restrict__ pred,
    const unsigned char* __restrict__ mask,
    const int* __restrict__ classes,
    float* __restrict__ ws)
{
    const int nk  = blockIdx.x / BPN;
    const int blk = blockIdx.x % BPN;
    const int n   = nk / K_OBJ;
    const int c   = classes[nk];

    const f32x4* __restrict__ embv =
        (const f32x4*)(pred + (size_t)(n * C_CH + c) * HW);
    const u32x4* __restrict__ mv =
        (const u32x4*)(mask + (size_t)nk * HW);

    const int base = blk * BT + threadIdx.x;
    const int i0 = base;
    const int i1 = base + SPAN;

    // Issue ALL loads before any consumption: 2 x u32x4 + 8 x f32x4
    // = 160 B/lane in flight, non-temporal (streams are read once).
    const u32x4 m0  = __builtin_nontemporal_load(&mv[i0]);
    const u32x4 m1  = __builtin_nontemporal_load(&mv[i1]);
    const f32x4 e00 = __builtin_nontemporal_load(&embv[4*i0 + 0]);
    const f32x4 e01 = __builtin_nontemporal_load(&embv[4*i0 + 1]);
    const f32x4 e02 = __builtin_nontemporal_load(&embv[4*i0 + 2]);
    const f32x4 e03 = __builtin_nontemporal_load(&embv[4*i0 + 3]);
    const f32x4 e10 = __builtin_nontemporal_load(&embv[4*i1 + 0]);
    const f32x4 e11 = __builtin_nontemporal_load(&embv[4*i1 + 1]);
    const f32x4 e12 = __builtin_nontemporal_load(&embv[4*i1 + 2]);
    const f32x4 e13 = __builtin_nontemporal_load(&embv[4*i1 + 3]);

    unsigned int cnt_i = 0;
    float s = 0.0f, s2 = 0.0f;

#define ACCB(w, b, e) do {                                   \
        float v_ = (((w) >> (8*(b))) & 1u) ? (e) : 0.0f;     \
        s += v_; s2 = fmaf(v_, (e), s2);                     \
    } while (0)

    {
        unsigned int t0 = m0.x + m0.y + m0.z + m0.w;  // per-byte sums <= 4
        unsigned int t1 = m1.x + m1.y + m1.z + m1.w;
        cnt_i += ((t0 + t1) * 0x01010101u) >> 24;     // sum of 32 mask bytes

        ACCB(m0.x,0,e00.x); ACCB(m0.x,1,e00.y); ACCB(m0.x,2,e00.z); ACCB(m0.x,3,e00.w);
        ACCB(m0.y,0,e01.x); ACCB(m0.y,1,e01.y); ACCB(m0.y,2,e01.z); ACCB(m0.y,3,e01.w);
        ACCB(m0.z,0,e02.x); ACCB(m0.z,1,e02.y); ACCB(m0.z,2,e02.z); ACCB(m0.z,3,e02.w);
        ACCB(m0.w,0,e03.x); ACCB(m0.w,1,e03.y); ACCB(m0.w,2,e03.z); ACCB(m0.w,3,e03.w);

        ACCB(m1.x,0,e10.x); ACCB(m1.x,1,e10.y); ACCB(m1.x,2,e10.z); ACCB(m1.x,3,e10.w);
        ACCB(m1.y,0,e11.x); ACCB(m1.y,1,e11.y); ACCB(m1.y,2,e11.z); ACCB(m1.y,3,e11.w);
        ACCB(m1.z,0,e12.x); ACCB(m1.z,1,e12.y); ACCB(m1.z,2,e12.z); ACCB(m1.z,3,e12.w);
        ACCB(m1.w,0,e13.x); ACCB(m1.w,1,e13.y); ACCB(m1.w,2,e13.z); ACCB(m1.w,3,e13.w);
    }
#undef ACCB

    float cnt = (float)cnt_i;
    #pragma unroll
    for (int off = 32; off > 0; off >>= 1) {
        cnt += __shfl_down(cnt, off);
        s   += __shfl_down(s,   off);
        s2  += __shfl_down(s2,  off);
    }

    __shared__ float sm[3][BT / 64];
    const int lane = threadIdx.x & 63;
    const int wv   = threadIdx.x >> 6;
    if (lane == 0) { sm[0][wv] = cnt; sm[1][wv] = s; sm[2][wv] = s2; }
    __syncthreads();
    if (threadIdx.x == 0) {
        float tc = 0.f, ts = 0.f, t2 = 0.f;
        #pragma unroll
        for (int w = 0; w < BT / 64; ++w) {
            tc += sm[0][w]; ts += sm[1][w]; t2 += sm[2][w];
        }
        float* dst = ws + (size_t)blk * 3 * NK;
        dst[0 * NK + nk] = tc;
        dst[1 * NK + nk] = ts;
        dst[2 * NK + nk] = t2;
    }
}

// One wave (64 threads), one thread per (n,k).
__global__ void finalize(const float* __restrict__ ws,
                         const int* __restrict__ classes,
                         float* __restrict__ out)
{
    const int t = threadIdx.x;          // 0..63
    float cnt = 0.f, s = 0.f, s2 = 0.f;
    for (int blk = 0; blk < BPN; ++blk) {
        const float* src = ws + (size_t)blk * 3 * NK;
        cnt += src[0 * NK + t];
        s   += src[1 * NK + t];
        s2  += src[2 * NK + t];
    }
    const bool valid = cnt > 0.0f;
    const float safe = valid ? cnt : 1.0f;
    const float mean = valid ? s / safe : 0.0f;
    const float var  = valid ? s2 / safe - mean * mean : 0.0f;

    __shared__ float smean[NK];
    __shared__ int   scls[NK];
    smean[t] = mean;
    scls[t]  = classes[t];
    __syncthreads();

    const int j  = t & 31;              // instance within image
    const int nb = t & 32;              // image base (0 or 32)
    float part = (mean * mean + var) * (1.0f / K_OBJ);   // reg + intra share
    const int cj = scls[t];
    for (int k = j + 1; k < K_OBJ; ++k) {
        if (scls[nb + k] == cj) {
            float d = mean - smean[nb + k];
            float val = 1.0f - d * d;
            part += (val > 0.0f) ? val : 0.0f;
        }
    }
    // full 64-lane reduce -> I0 + I1
    #pragma unroll
    for (int off = 32; off > 0; off >>= 1) part += __shfl_down(part, off);
    if (t == 0) out[0] = part * (0.1f / N_IMG);
}

extern "C" void kernel_launch(void* const* d_in, const int* in_sizes, int n_in,
                              void* d_out, int out_size, void* d_ws, size_t ws_size,
                              hipStream_t stream) {
    const float* pred = (const float*)d_in[0];
    const unsigned char* mask = (const unsigned char*)d_in[1];
    const int* classes = (const int*)d_in[2];
    float* out = (float*)d_out;
    float* ws = (float*)d_ws;

    partial_kernel<<<NK * BPN, BT, 0, stream>>>(pred, mask, classes, ws);
    finalize<<<1, 64, 0, stream>>>(ws, classes, out);
}

// Round 7
// 21.839 us; speedup vs baseline: 4.1201x; 1.2847x over previous
//
#include <hip/hip_runtime.h>

// Problem constants (from reference setup_inputs):
//   pred_emb:   (N=2, C=80, H=512, W=512) float32
//   gt_objmask: (N=2, K=32, H=512, W=512) bool (1 byte/elem)
//   gt_classes: (N=2, K=32) int32
#define N_IMG 2
#define K_OBJ 32
#define C_CH  80
#define HW    (512 * 512)
#define NK    (N_IMG * K_OBJ)

#define BPN 32                    // blocks per (n,k)
#define BT  256                   // threads per block
#define SPAN (BPN * BT)           // 8192 thread-slots per (n,k)
#define NV16 (HW / 16)            // 16384 16-elem groups per (n,k)
#define ITERS (NV16 / SPAN)       // = 2, compile-time

// ws layout: ws[blk][comp][nk], comp in {cnt,s,s2}; 32*3*64 floats = 24 KB.
// Every slot is written every call by partial_kernel, so no zeroing needed.

__global__ __launch_bounds__(BT) void partial_kernel(
    const float* __restrict__ pred,
    const unsigned char* __restrict__ mask,
    const int* __restrict__ classes,
    float* __restrict__ ws)
{
    const int nk  = blockIdx.x / BPN;
    const int blk = blockIdx.x % BPN;
    const int n   = nk / K_OBJ;
    const int c   = classes[nk];

    const float4* __restrict__ embv =
        (const float4*)(pred + (size_t)(n * C_CH + c) * HW);
    const uint4* __restrict__ mv =
        (const uint4*)(mask + (size_t)nk * HW);

    unsigned int cnt_i = 0;
    float s = 0.0f, s2 = 0.0f;

    const int base = blk * BT + threadIdx.x;

#define ACCB(w, b, e) do {                                   \
        float v_ = (((w) >> (8*(b))) & 1u) ? (e) : 0.0f;     \
        s += v_; s2 = fmaf(v_, (e), s2);                     \
    } while (0)

    #pragma unroll
    for (int it = 0; it < ITERS; ++it) {
        const int i = base + it * SPAN;
        // lane covers 64 contiguous bytes of emb (4 float4) + 16 mask bytes
        const uint4  m  = mv[i];
        const float4 e0 = embv[4*i + 0];
        const float4 e1 = embv[4*i + 1];
        const float4 e2 = embv[4*i + 2];
        const float4 e3 = embv[4*i + 3];

        unsigned int t = m.x + m.y + m.z + m.w;   // per-byte sums <= 4
        cnt_i += (t * 0x01010101u) >> 24;         // sum of 16 mask bytes

        ACCB(m.x,0,e0.x); ACCB(m.x,1,e0.y); ACCB(m.x,2,e0.z); ACCB(m.x,3,e0.w);
        ACCB(m.y,0,e1.x); ACCB(m.y,1,e1.y); ACCB(m.y,2,e1.z); ACCB(m.y,3,e1.w);
        ACCB(m.z,0,e2.x); ACCB(m.z,1,e2.y); ACCB(m.z,2,e2.z); ACCB(m.z,3,e2.w);
        ACCB(m.w,0,e3.x); ACCB(m.w,1,e3.y); ACCB(m.w,2,e3.z); ACCB(m.w,3,e3.w);
    }
#undef ACCB

    float cnt = (float)cnt_i;
    #pragma unroll
    for (int off = 32; off > 0; off >>= 1) {
        cnt += __shfl_down(cnt, off);
        s   += __shfl_down(s,   off);
        s2  += __shfl_down(s2,  off);
    }

    __shared__ float sm[3][BT / 64];
    const int lane = threadIdx.x & 63;
    const int wv   = threadIdx.x >> 6;
    if (lane == 0) { sm[0][wv] = cnt; sm[1][wv] = s; sm[2][wv] = s2; }
    __syncthreads();
    if (threadIdx.x == 0) {
        float tc = 0.f, ts = 0.f, t2 = 0.f;
        #pragma unroll
        for (int w = 0; w < BT / 64; ++w) {
            tc += sm[0][w]; ts += sm[1][w]; t2 += sm[2][w];
        }
        float* dst = ws + (size_t)blk * 3 * NK;
        dst[0 * NK + nk] = tc;
        dst[1 * NK + nk] = ts;
        dst[2 * NK + nk] = t2;
    }
}

// 256 threads: 4 groups x 64 nk; group g sums blocks [8g, 8g+8), then LDS
// combine; first wave (64 threads) does mean/var + the tiny epilogue.
__global__ __launch_bounds__(256) void finalize(
    const float* __restrict__ ws,
    const int* __restrict__ classes,
    float* __restrict__ out)
{
    const int t  = threadIdx.x;
    const int nk = t & 63;
    const int g  = t >> 6;               // 0..3

    float cnt = 0.f, s = 0.f, s2 = 0.f;
    #pragma unroll
    for (int b = 0; b < BPN / 4; ++b) {
        const float* src = ws + (size_t)(g * (BPN / 4) + b) * 3 * NK;
        cnt += src[0 * NK + nk];
        s   += src[1 * NK + nk];
        s2  += src[2 * NK + nk];
    }

    __shared__ float pc[4][NK], ps[4][NK], p2[4][NK];
    pc[g][nk] = cnt; ps[g][nk] = s; p2[g][nk] = s2;
    __syncthreads();

    __shared__ float smean[NK];
    __shared__ int   scls[NK];
    float mean = 0.f, var = 0.f;
    if (t < NK) {
        float fc = pc[0][t] + pc[1][t] + pc[2][t] + pc[3][t];
        float fs = ps[0][t] + ps[1][t] + ps[2][t] + ps[3][t];
        float f2 = p2[0][t] + p2[1][t] + p2[2][t] + p2[3][t];
        const bool valid = fc > 0.0f;
        const float safe = valid ? fc : 1.0f;
        mean = valid ? fs / safe : 0.0f;
        var  = valid ? f2 / safe - mean * mean : 0.0f;
        smean[t] = mean;
        scls[t]  = classes[t];
    }
    __syncthreads();

    if (t < NK) {
        const int j  = t & 31;           // instance within image
        const int nb = t & 32;           // image base (0 or 32)
        float part = (mean * mean + var) * (1.0f / K_OBJ);  // reg+intra share
        const int cj = scls[t];
        for (int k = j + 1; k < K_OBJ; ++k) {
            if (scls[nb + k] == cj) {
                float d = mean - smean[nb + k];
                float val = 1.0f - d * d;
                part += (val > 0.0f) ? val : 0.0f;
            }
        }
        #pragma unroll
        for (int off = 32; off > 0; off >>= 1) part += __shfl_down(part, off);
        if (t == 0) out[0] = part * (0.1f / N_IMG);
    }
}

extern "C" void kernel_launch(void* const* d_in, const int* in_sizes, int n_in,
                              void* d_out, int out_size, void* d_ws, size_t ws_size,
                              hipStream_t stream) {
    const float* pred = (const float*)d_in[0];
    const unsigned char* mask = (const unsigned char*)d_in[1];
    const int* classes = (const int*)d_in[2];
    float* out = (float*)d_out;
    float* ws = (float*)d_ws;

    partial_kernel<<<NK * BPN, BT, 0, stream>>>(pred, mask, classes, ws);
    finalize<<<1, 256, 0, stream>>>(ws, classes, out);
}